// Round 5
// baseline (5000.581 us; speedup 1.0000x reference)
//
#include <hip/hip_runtime.h>
#include <hip/hip_bf16.h>
#include <math.h>

#define BH 64
#define NSEQ 8192
#define DHEAD 64
#define M 128
#define LGRP 64
#define NC 8
#define CHUNK (NSEQ / NC)   // 1024
#define NSWEEP 10
#define NROUND 127
#define RCOND 1.52587890625e-4   // 10 * 128 * eps_f32  (jax f32 pinv rtol)

// ---------------- Kernel A: landmarks (f64 pooling, q scaled by 1/8) ----------------
__global__ __launch_bounds__(64) void lm_kernel(const float* __restrict__ q,
                                                const float* __restrict__ k,
                                                double* __restrict__ ql64,
                                                double* __restrict__ kl64,
                                                float* __restrict__ qlf32,
                                                float* __restrict__ klf32) {
    int idx = blockIdx.x;            // 0..16383
    int tensor = idx >> 13;          // 0 = q, 1 = k
    int g = idx & 8191;
    int head = g >> 7, m = g & 127;
    int d = threadIdx.x;
    const float* src = tensor ? k : q;
    const float* base = src + ((size_t)head * NSEQ + (size_t)m * LGRP) * DHEAD + d;
    double s = 0.0;
    #pragma unroll 8
    for (int r = 0; r < LGRP; ++r) s += (double)base[(size_t)r * DHEAD];
    s *= (1.0 / LGRP);
    if (!tensor) s *= 0.125;         // q / sqrt(64)
    size_t o = (size_t)head * M * DHEAD + (size_t)m * DHEAD + d;
    if (!tensor) { ql64[o] = s; qlf32[o] = (float)s; }
    else         { kl64[o] = s; klf32[o] = (float)s; }
}

// ---------------- Kernel B: S = softmax(ql @ kl^T) f64, stored COLUMN-major ----------------
__global__ __launch_bounds__(512) void s_kernel(const double* __restrict__ ql64,
                                                const double* __restrict__ kl64,
                                                double* __restrict__ Sg) {
    extern __shared__ double lds[];      // qlds[8192] | klds[8192]  (128 KB)
    double* qlds = lds;
    double* klds = lds + M * DHEAD;
    int head = blockIdx.x;
    int t = threadIdx.x;
    const double2* qg = (const double2*)(ql64 + (size_t)head * M * DHEAD);
    const double2* kg = (const double2*)(kl64 + (size_t)head * M * DHEAD);
    for (int e = t; e < M * DHEAD / 2; e += 512) {
        ((double2*)qlds)[e] = qg[e];
        ((double2*)klds)[e] = kg[e];
    }
    __syncthreads();
    int tr = t >> 4, tc = t & 15;        // rows 4tr..+4, cols 8tc..+8
    double acc[4][8];
    #pragma unroll
    for (int i = 0; i < 4; ++i)
        #pragma unroll
        for (int j = 0; j < 8; ++j) acc[i][j] = 0.0;
    for (int dc = 0; dc < DHEAD; dc += 4) {
        double qreg[4][4], kreg[8][4];
        #pragma unroll
        for (int i = 0; i < 4; ++i)
            #pragma unroll
            for (int d = 0; d < 4; ++d) qreg[i][d] = qlds[(4 * tr + i) * DHEAD + dc + d];
        #pragma unroll
        for (int j = 0; j < 8; ++j)
            #pragma unroll
            for (int d = 0; d < 4; ++d) kreg[j][d] = klds[(8 * tc + j) * DHEAD + dc + d];
        #pragma unroll
        for (int i = 0; i < 4; ++i)
            #pragma unroll
            for (int j = 0; j < 8; ++j)
                #pragma unroll
                for (int d = 0; d < 4; ++d) acc[i][j] += qreg[i][d] * kreg[j][d];
    }
    double* So = Sg + (size_t)head * M * M;
    #pragma unroll
    for (int i = 0; i < 4; ++i) {
        double mx = acc[i][0];
        #pragma unroll
        for (int j = 1; j < 8; ++j) mx = fmax(mx, acc[i][j]);
        mx = fmax(mx, __shfl_xor(mx, 1));
        mx = fmax(mx, __shfl_xor(mx, 2));
        mx = fmax(mx, __shfl_xor(mx, 4));
        mx = fmax(mx, __shfl_xor(mx, 8));
        double sum = 0.0;
        #pragma unroll
        for (int j = 0; j < 8; ++j) { acc[i][j] = exp(acc[i][j] - mx); sum += acc[i][j]; }
        sum += __shfl_xor(sum, 1); sum += __shfl_xor(sum, 2);
        sum += __shfl_xor(sum, 4); sum += __shfl_xor(sum, 8);
        double inv = 1.0 / sum;
        #pragma unroll
        for (int j = 0; j < 8; ++j)
            So[(size_t)(8 * tc + j) * M + 4 * tr + i] = acc[i][j] * inv;   // col-major
    }
}

// ---------------- Fused: register-systolic Jacobi (blocks 0..63) || B@v (blocks 64..319) ----
// Jacobi: 64 pair-groups x 8 lanes; each group holds 2 columns in VGPRs (16 f64/lane each).
// Circle-method round-robin: A-cols shift left one group, B-cols shift right, per round.
// Intra-wave moves via __shfl(+-8); wave-boundary columns via small double-buffered LDS.
struct JacobiLds {
    double bufA[2][8][128];   // [parity][wave][j*8+s]
    double bufB[2][8][128];
    double norms2[M];
    double maxn2;
};

__global__ __launch_bounds__(512) void fused_kernel(const double* __restrict__ Sg,
                                                    double* __restrict__ Wcol,
                                                    const float* __restrict__ k,
                                                    const float* __restrict__ v,
                                                    const float* __restrict__ qlf32,
                                                    double* __restrict__ numd,
                                                    double* __restrict__ dend) {
    __shared__ JacobiLds L;
    if (blockIdx.x < BH) {
        // ================= Jacobi =================
        int head = blockIdx.x;
        int t = threadIdx.x;
        int G = t >> 3, s = t & 7, w = t >> 6, gw = G & 7, l = t & 63;
        const double* Sh = Sg + (size_t)head * M * M;
        double A[16], B[16];
        #pragma unroll
        for (int j = 0; j < 16; ++j) {
            A[j] = Sh[(size_t)(2 * G) * M + 16 * s + j];
            B[j] = Sh[(size_t)(2 * G + 1) * M + 16 * s + j];
        }
        int srcA = (l + 8) & 63;
        int srcB = (l - 8) & 63;
        for (int rr = 0; rr < NSWEEP * NROUND; ++rr) {
            // dots (d = |B|^2 - |A|^2, c = A.B), reduced over the 8-lane group
            double pa = 0.0, pb = 0.0, pc = 0.0;
            #pragma unroll
            for (int j = 0; j < 16; ++j) {
                pa += A[j] * A[j]; pb += B[j] * B[j]; pc += A[j] * B[j];
            }
            double d = pb - pa, c = pc;
            d += __shfl_xor(d, 1); c += __shfl_xor(c, 1);
            d += __shfl_xor(d, 2); c += __shfl_xor(c, 2);
            d += __shfl_xor(d, 4); c += __shfl_xor(c, 4);
            if (c * c > 1e-26 * d * d) {   // skip |t| < ~1e-13 rotations (and c==0)
                double zeta = d / (2.0 * c);
                double tt = (zeta >= 0.0 ? 1.0 : -1.0) / (fabs(zeta) + sqrt(1.0 + zeta * zeta));
                double cs = 1.0 / sqrt(1.0 + tt * tt);
                double sn = cs * tt;
                #pragma unroll
                for (int j = 0; j < 16; ++j) {
                    double na = cs * A[j] - sn * B[j];
                    double nb = sn * A[j] + cs * B[j];
                    A[j] = na; B[j] = nb;
                }
            }
            // exchange (circle method): top[i]<-top[i+1], bottom[i]<-bottom[i-1],
            // top[0] fixed, bottom[0]<-top[1], top[63]<-bottom[63]
            int par = rr & 1;
            if (gw == 0) {
                #pragma unroll
                for (int j = 0; j < 16; ++j) L.bufA[par][w][j * 8 + s] = A[j];
            }
            if (gw == 7) {
                #pragma unroll
                for (int j = 0; j < 16; ++j) L.bufB[par][w][j * 8 + s] = B[j];
            }
            __syncthreads();
            #pragma unroll
            for (int j = 0; j < 16; ++j) {
                double tA = __shfl(A[j], srcA);
                double tB = __shfl(B[j], srcB);
                double nA, nB;
                if (G == 63)      nA = B[j];
                else if (gw == 7) nA = L.bufA[par][w + 1][j * 8 + s];
                else if (G == 0)  nA = A[j];
                else              nA = tA;
                if (G == 0)       nB = tA;
                else if (gw == 0) nB = L.bufB[par][w - 1][j * 8 + s];
                else              nB = tB;
                A[j] = nA; B[j] = nB;
            }
        }
        // norms^2 (= sigma^2), truncation, W = u / sigma^2-norm (i.e. u/sigma * 1/sigma)
        double pa = 0.0, pb = 0.0;
        #pragma unroll
        for (int j = 0; j < 16; ++j) { pa += A[j] * A[j]; pb += B[j] * B[j]; }
        pa += __shfl_xor(pa, 1); pb += __shfl_xor(pb, 1);
        pa += __shfl_xor(pa, 2); pb += __shfl_xor(pb, 2);
        pa += __shfl_xor(pa, 4); pb += __shfl_xor(pb, 4);
        if (s == 0) { L.norms2[2 * G] = pa; L.norms2[2 * G + 1] = pb; }
        __syncthreads();
        if (t < 64) {
            double mm = fmax(L.norms2[t], L.norms2[t + 64]);
            for (int off = 32; off > 0; off >>= 1) mm = fmax(mm, __shfl_down(mm, off));
            if (t == 0) L.maxn2 = mm;
        }
        __syncthreads();
        double cut2 = L.maxn2 * (RCOND * RCOND);
        double ia = (pa > cut2) ? 1.0 / pa : 0.0;
        double ib = (pb > cut2) ? 1.0 / pb : 0.0;
        double* Wh = Wcol + (size_t)head * M * M;
        #pragma unroll
        for (int j = 0; j < 16; ++j) {
            Wh[(size_t)(2 * G) * M + 16 * s + j] = A[j] * ia;
            Wh[(size_t)(2 * G + 1) * M + 16 * s + j] = B[j] * ib;
        }
    } else {
        // ================= B@v partials =================
        int bb = blockIdx.x - BH;       // 0..255
        int t = threadIdx.x;
        int cid = bb * 2 + (t >> 8);    // global chunk-task 0..511
        int head = cid >> 3;
        int chunk = cid & 7;
        int tl = t & 255;
        int m = tl >> 1, h = t & 1;
        float ql[32];
        const float* qb = qlf32 + ((size_t)head * M + m) * DHEAD + h * 32;
        #pragma unroll
        for (int d = 0; d < 32; ++d) ql[d] = qb[d];
        float acc32[32]; double acc64[32];
        #pragma unroll
        for (int d = 0; d < 32; ++d) { acc32[d] = 0.f; acc64[d] = 0.0; }
        float dacc32 = 0.f; double dacc64 = 0.0;
        const float* kb = k + ((size_t)head * NSEQ + (size_t)chunk * CHUNK) * DHEAD + h * 32;
        const float* vb = v + ((size_t)head * NSEQ + (size_t)chunk * CHUNK) * DHEAD + h * 32;
        for (int key = 0; key < CHUNK; ++key) {
            const float4* kr = (const float4*)(kb + (size_t)key * DHEAD);
            float z = 0.f;
            #pragma unroll
            for (int c = 0; c < 8; ++c) {
                float4 kk = kr[c];
                z += ql[4 * c] * kk.x + ql[4 * c + 1] * kk.y + ql[4 * c + 2] * kk.z + ql[4 * c + 3] * kk.w;
            }
            z += __shfl_xor(z, 1);
            float e = __expf(z);
            dacc32 += e;
            const float4* vr = (const float4*)(vb + (size_t)key * DHEAD);
            #pragma unroll
            for (int c = 0; c < 8; ++c) {
                float4 vv = vr[c];
                acc32[4 * c]     += e * vv.x;
                acc32[4 * c + 1] += e * vv.y;
                acc32[4 * c + 2] += e * vv.z;
                acc32[4 * c + 3] += e * vv.w;
            }
            if (((key + 1) & 127) == 0) {
                #pragma unroll
                for (int d = 0; d < 32; ++d) { acc64[d] += (double)acc32[d]; acc32[d] = 0.f; }
                dacc64 += (double)dacc32; dacc32 = 0.f;
            }
        }
        size_t ob = (((size_t)head * NC + chunk) * M + m) * DHEAD + h * 32;
        #pragma unroll
        for (int d = 0; d < 32; ++d) numd[ob + d] = acc64[d];
        if (h == 0) dend[((size_t)head * NC + chunk) * M + m] = dacc64;
    }
}

// ---------------- Kernel E: fused  Bv reduce -> W^T -> W -> S^T  (f64, ABv out f32) ----
__global__ __launch_bounds__(512) void apply_kernel(const double* __restrict__ numd,
                                                    const double* __restrict__ dend,
                                                    const double* __restrict__ Wcol,
                                                    const double* __restrict__ Sg,
                                                    float* __restrict__ ABvf32) {
    extern __shared__ double lds[];
    double* A_ = lds;                 // [128][66]
    double* B_ = lds + M * 66;
    __shared__ double dsum[M];
    int head = blockIdx.x;
    int t = threadIdx.x;
    if (t < M) {
        double s = 0.0;
        #pragma unroll
        for (int c = 0; c < NC; ++c) s += dend[((size_t)head * NC + c) * M + t];
        dsum[t] = s;
    }
    __syncthreads();
    for (int e = t; e < M * DHEAD; e += 512) {
        int mm = e >> 6;
        double s = 0.0;
        #pragma unroll
        for (int c = 0; c < NC; ++c) s += numd[((size_t)head * NC + c) * (M * DHEAD) + e];
        A_[mm * 66 + (e & 63)] = s / dsum[mm];
    }
    __syncthreads();
    int i = t >> 3, qd = t & 7;
    const double* Wb = Wcol + (size_t)head * M * M;
    const double* Sb = Sg + (size_t)head * M * M;
    {   // stage 1: B = W^T A
        double a0[8], a1[8];
        #pragma unroll
        for (int d = 0; d < 8; ++d) { a0[d] = 0.0; a1[d] = 0.0; }
        for (int r = 0; r < M; ++r) {
            double m0 = Wb[(size_t)i * M + r];
            double m1 = Wb[(size_t)(i + 64) * M + r];
            #pragma unroll
            for (int d = 0; d < 8; ++d) {
                double xv = A_[r * 66 + qd * 8 + d];
                a0[d] += m0 * xv; a1[d] += m1 * xv;
            }
        }
        #pragma unroll
        for (int d = 0; d < 8; ++d) {
            B_[i * 66 + qd * 8 + d] = a0[d];
            B_[(i + 64) * 66 + qd * 8 + d] = a1[d];
        }
    }
    __syncthreads();
    {   // stage 2: A = W B
        double a0[8], a1[8];
        #pragma unroll
        for (int d = 0; d < 8; ++d) { a0[d] = 0.0; a1[d] = 0.0; }
        for (int r = 0; r < M; ++r) {
            double m0 = Wb[(size_t)r * M + i];
            double m1 = Wb[(size_t)r * M + i + 64];
            #pragma unroll
            for (int d = 0; d < 8; ++d) {
                double xv = B_[r * 66 + qd * 8 + d];
                a0[d] += m0 * xv; a1[d] += m1 * xv;
            }
        }
        #pragma unroll
        for (int d = 0; d < 8; ++d) {
            A_[i * 66 + qd * 8 + d] = a0[d];
            A_[(i + 64) * 66 + qd * 8 + d] = a1[d];
        }
    }
    __syncthreads();
    {   // stage 3: ABv = S^T A
        double a0[8], a1[8];
        #pragma unroll
        for (int d = 0; d < 8; ++d) { a0[d] = 0.0; a1[d] = 0.0; }
        for (int r = 0; r < M; ++r) {
            double m0 = Sb[(size_t)i * M + r];
            double m1 = Sb[(size_t)(i + 64) * M + r];
            #pragma unroll
            for (int d = 0; d < 8; ++d) {
                double xv = A_[r * 66 + qd * 8 + d];
                a0[d] += m0 * xv; a1[d] += m1 * xv;
            }
        }
        float* ob = ABvf32 + (size_t)head * M * DHEAD;
        #pragma unroll
        for (int d = 0; d < 8; ++d) {
            ob[i * DHEAD + qd * 8 + d] = (float)a0[d];
            ob[(i + 64) * DHEAD + qd * 8 + d] = (float)a1[d];
        }
    }
}

// ---------------- Kernel F: out = softmax(q @ kl^T) @ ABv  (f32, 2-row tiling) --------
__global__ __launch_bounds__(512) void out_kernel(const float* __restrict__ q,
                                                  const float* __restrict__ klf32,
                                                  const float* __restrict__ ABvf32,
                                                  float* __restrict__ out) {
    __shared__ float kls[M * DHEAD];
    __shared__ float avs[M * DHEAD];
    int head = blockIdx.x >> 4;
    int tile = blockIdx.x & 15;
    int t = threadIdx.x;
    for (int e = t; e < M * DHEAD; e += 512) {
        kls[e] = klf32[(size_t)head * M * DHEAD + e];
        avs[e] = ABvf32[(size_t)head * M * DHEAD + e];
    }
    __syncthreads();
    int rl = t >> 1, h = t & 1;
    size_t row0 = (size_t)head * NSEQ + (size_t)tile * 512 + rl;
    size_t row1 = row0 + 256;
    const float4* qr0 = (const float4*)(q + row0 * DHEAD + h * 32);
    const float4* qr1 = (const float4*)(q + row1 * DHEAD + h * 32);
    float4 qa[8], qb[8];
    #pragma unroll
    for (int c = 0; c < 8; ++c) {
        float4 x = qr0[c];
        x.x *= 0.125f; x.y *= 0.125f; x.z *= 0.125f; x.w *= 0.125f;
        qa[c] = x;
        float4 y = qr1[c];
        y.x *= 0.125f; y.y *= 0.125f; y.z *= 0.125f; y.w *= 0.125f;
        qb[c] = y;
    }
    float acc0[32], acc1[32];
    #pragma unroll
    for (int d = 0; d < 32; ++d) { acc0[d] = 0.f; acc1[d] = 0.f; }
    float d0 = 0.f, d1 = 0.f;
    for (int mm = 0; mm < M; ++mm) {
        const float4* kr = (const float4*)(kls + mm * DHEAD + h * 32);
        float z0 = 0.f, z1 = 0.f;
        #pragma unroll
        for (int c = 0; c < 8; ++c) {
            float4 kk = kr[c];
            z0 += qa[c].x * kk.x + qa[c].y * kk.y + qa[c].z * kk.z + qa[c].w * kk.w;
            z1 += qb[c].x * kk.x + qb[c].y * kk.y + qb[c].z * kk.z + qb[c].w * kk.w;
        }
        z0 += __shfl_xor(z0, 1);
        z1 += __shfl_xor(z1, 1);
        float e0 = __expf(z0), e1 = __expf(z1);
        d0 += e0; d1 += e1;
        const float4* ar = (const float4*)(avs + mm * DHEAD + h * 32);
        #pragma unroll
        for (int c = 0; c < 8; ++c) {
            float4 av = ar[c];
            acc0[4 * c]     += e0 * av.x; acc0[4 * c + 1] += e0 * av.y;
            acc0[4 * c + 2] += e0 * av.z; acc0[4 * c + 3] += e0 * av.w;
            acc1[4 * c]     += e1 * av.x; acc1[4 * c + 1] += e1 * av.y;
            acc1[4 * c + 2] += e1 * av.z; acc1[4 * c + 3] += e1 * av.w;
        }
    }
    float i0 = 1.f / d0, i1 = 1.f / d1;
    float* o0 = out + row0 * DHEAD + h * 32;
    float* o1 = out + row1 * DHEAD + h * 32;
    #pragma unroll
    for (int d = 0; d < 32; ++d) { o0[d] = acc0[d] * i0; o1[d] = acc1[d] * i1; }
}

extern "C" void kernel_launch(void* const* d_in, const int* in_sizes, int n_in,
                              void* d_out, int out_size, void* d_ws, size_t ws_size,
                              hipStream_t stream) {
    const float* q = (const float*)d_in[0];
    const float* k = (const float*)d_in[1];
    const float* v = (const float*)d_in[2];
    float* out = (float*)d_out;
    char* ws = (char*)d_ws;
    double* numd  = (double*)(ws + 0);            // 32 MB
    double* ql64  = (double*)(ws + 0);            //  4 MB (aliases numd; dead before fused)
    double* kl64  = (double*)(ws + 4194304);      //  4 MB (aliases numd; dead before fused)
    double* dend  = (double*)(ws + 33554432);     //  512 KB
    float*  qlf32 = (float*)(ws + 34078720);      //  2 MB
    float*  klf32 = (float*)(ws + 36175872);      //  2 MB
    double* Sg    = (double*)(ws + 38273024);     //  8 MB  (S column-major per head)
    double* Wcol  = (double*)(ws + 46661632);     //  8 MB
    float*  ABvf32= (float*)(ws + 55050240);      //  2 MB

    lm_kernel<<<16384, 64, 0, stream>>>(q, k, ql64, kl64, qlf32, klf32);
    s_kernel<<<BH, 512, 2 * M * DHEAD * 8, stream>>>(ql64, kl64, Sg);
    fused_kernel<<<BH + 256, 512, 0, stream>>>(Sg, Wcol, k, v, qlf32, numd, dend);
    apply_kernel<<<BH, 512, 2 * M * 66 * 8, stream>>>(numd, dend, Wcol, Sg, ABvf32);
    out_kernel<<<BH * 16, 512, 0, stream>>>(q, klf32, ABvf32, out);
}